// Round 1
// baseline (1147.355 us; speedup 1.0000x reference)
//
#include <hip/hip_runtime.h>

#define BD 4
#define TD 2048
#define DD 2048
#define DID 4096
#define MD (BD*TD)   // 8192 rows

typedef float f32x4 __attribute__((ext_vector_type(4)));
typedef short s16x8 __attribute__((ext_vector_type(8)));
typedef unsigned short u16;
typedef unsigned short u16x4 __attribute__((ext_vector_type(4)));
typedef unsigned short u16x8 __attribute__((ext_vector_type(8)));

__device__ __forceinline__ float bf2f(u16 u) {
    union { unsigned int i; float f; } v; v.i = ((unsigned int)u) << 16; return v.f;
}
__device__ __forceinline__ u16 f2bf(float f) {
    union { float f; unsigned int i; } v; v.f = f;
    unsigned int r = v.i + 0x7fffu + ((v.i >> 16) & 1u);   // RNE
    return (u16)(r >> 16);
}
__device__ __forceinline__ float sigm(float x) { return 1.f / (1.f + __expf(-x)); }

// MFMA via inline asm (sidesteps builtin vector-type signature differences).
// gfx950 unified VGPR/AGPR: plain "v" operands are valid for C/D.
__device__ __forceinline__ void mfma16(f32x4& acc, s16x8 a, s16x8 b) {
    asm("v_mfma_f32_16x16x32_bf16 %0, %1, %2, %0" : "+v"(acc) : "v"(a), "v"(b));
}

// async global->LDS, 16B per lane; LDS dest must be wave-uniform base + lane*16
__device__ __forceinline__ void gload16(const u16* g, u16* l) {
    __builtin_amdgcn_global_load_lds((__attribute__((address_space(1))) void*)(g),
                                     (__attribute__((address_space(3))) void*)(l),
                                     16, 0, 0);
}

// ---------------- fp32 -> bf16 convert (weights) ----------------
__global__ __launch_bounds__(256) void cvt_bf16(const float4* __restrict__ in,
                                                u16x4* __restrict__ out, int n4) {
    int i = blockIdx.x * blockDim.x + threadIdx.x;
    int stride = gridDim.x * blockDim.x;
    for (; i < n4; i += stride) {
        float4 v = in[i];
        u16x4 o = { f2bf(v.x), f2bf(v.y), f2bf(v.z), f2bf(v.w) };
        out[i] = o;
    }
}

// ---------------- RMSNorm: fp32 in -> bf16 out ----------------
__global__ __launch_bounds__(256) void rmsnorm_kernel(const float* __restrict__ x,
                                                      const float* __restrict__ w,
                                                      u16* __restrict__ out) {
    const int row = blockIdx.x;
    const int tid = threadIdx.x;
    const float4* x4 = (const float4*)(x + (size_t)row * DD);
    float4 a = x4[tid * 2], b = x4[tid * 2 + 1];
    float s = a.x*a.x + a.y*a.y + a.z*a.z + a.w*a.w
            + b.x*b.x + b.y*b.y + b.z*b.z + b.w*b.w;
#pragma unroll
    for (int off = 32; off >= 1; off >>= 1) s += __shfl_xor(s, off, 64);
    __shared__ float red[4];
    if ((tid & 63) == 0) red[tid >> 6] = s;
    __syncthreads();
    float tot = red[0] + red[1] + red[2] + red[3];
    float rs = rsqrtf(tot * (1.f / DD) + 1e-6f);
    const float4* w4 = (const float4*)w;
    float4 wa = w4[tid * 2], wb = w4[tid * 2 + 1];
    u16x8 o = { f2bf(a.x*rs*wa.x), f2bf(a.y*rs*wa.y), f2bf(a.z*rs*wa.z), f2bf(a.w*rs*wa.w),
                f2bf(b.x*rs*wb.x), f2bf(b.y*rs*wb.y), f2bf(b.z*rs*wb.z), f2bf(b.w*rs*wb.w) };
    *(u16x8*)(out + (size_t)row * DD + tid * 8) = o;
}

// ---------------- GEMM C = A(MxK) * B(NxK)^T, bf16 in, fp32 acc ----------------
// 128x128 tile, BK=32, 4 waves (2x2 of 64x64), 16x16x32 MFMA, global_load_lds staging.
// EPI 0: split-N {r=sigmoid(+b_r), g=sigmoid(+b_i), xp} -> 3 bf16 bufs (Dsub=D)
// EPI 1: outf = resid + c (fp32)
// EPI 2: split-N {silu(gate), up} -> 2 bf16 bufs (Dsub=DI)
template<int EPI>
__global__ __launch_bounds__(256)
void gemm_bt(const u16* __restrict__ A, const u16* __restrict__ Bw,
             int M, int N, int K,
             const float* __restrict__ bias0, const float* __restrict__ bias1,
             const float* resid, float* outf,
             u16* __restrict__ out0, u16* __restrict__ out1, u16* __restrict__ out2,
             int Dsub) {
    __shared__ __align__(16) u16 lA[128 * 32];
    __shared__ __align__(16) u16 lB[128 * 32];
    const int tid  = threadIdx.x;
    const int lane = tid & 63;
    const int wave = tid >> 6;
    const int brow = blockIdx.x * 128;
    const int bcol = blockIdx.y * 128;
    const int wr = (wave >> 1) << 6;      // wave row offset in tile
    const int wc = (wave & 1) << 6;       // wave col offset in tile
    const int sr = tid >> 2;              // staging row (0..63)
    const int sc = (tid & 3) << 3;        // staging col in elems (16B chunks)
    const u16* gA = A  + (size_t)(brow + sr) * K + sc;
    const u16* gB = Bw + (size_t)(bcol + sr) * K + sc;
    u16* lAp = lA + tid * 8;              // linear LDS dest (base + lane*16B)
    u16* lBp = lB + tid * 8;
    const int fr = lane & 15;
    const int kb = (lane >> 4) << 3;

    f32x4 acc[4][4];
#pragma unroll
    for (int i = 0; i < 4; ++i)
#pragma unroll
        for (int j = 0; j < 4; ++j)
            acc[i][j] = (f32x4){0.f, 0.f, 0.f, 0.f};

    for (int k0 = 0; k0 < K; k0 += 32) {
        gload16(gA + k0,          lAp);
        gload16(gA + 64 * K + k0, lAp + 64 * 32);
        gload16(gB + k0,          lBp);
        gload16(gB + 64 * K + k0, lBp + 64 * 32);
        __syncthreads();                  // compiler drains vmcnt before barrier
        s16x8 af[4], bq[4];
#pragma unroll
        for (int i = 0; i < 4; ++i)
            af[i] = *(const s16x8*)(lA + (wr + i * 16 + fr) * 32 + kb);
#pragma unroll
        for (int i = 0; i < 4; ++i)
            bq[i] = *(const s16x8*)(lB + (wc + i * 16 + fr) * 32 + kb);
#pragma unroll
        for (int i = 0; i < 4; ++i)
#pragma unroll
            for (int j = 0; j < 4; ++j)
                mfma16(acc[i][j], af[i], bq[j]);
        __syncthreads();
    }

    // MFMA-write -> VALU-read hazard fence (inline asm bypasses compiler's nop insertion)
#pragma unroll
    for (int i = 0; i < 4; ++i)
#pragma unroll
        for (int j = 0; j < 4; ++j)
            asm volatile("s_nop 7" : "+v"(acc[i][j]));

    const int r0 = brow + wr + ((lane >> 4) << 2);
    const int c0 = bcol + wc + fr;
#pragma unroll
    for (int i = 0; i < 4; ++i) {
#pragma unroll
        for (int j = 0; j < 4; ++j) {
            const int gcol = c0 + j * 16;
#pragma unroll
            for (int e = 0; e < 4; ++e) {
                const int grow = r0 + i * 16 + e;
                float c = acc[i][j][e];
                if (EPI == 0) {
                    if (gcol < Dsub) {
                        out0[(size_t)grow * Dsub + gcol] = f2bf(sigm(c + bias0[gcol]));
                    } else if (gcol < 2 * Dsub) {
                        out1[(size_t)grow * Dsub + (gcol - Dsub)] = f2bf(sigm(c + bias1[gcol - Dsub]));
                    } else {
                        out2[(size_t)grow * Dsub + (gcol - 2 * Dsub)] = f2bf(c);
                    }
                } else if (EPI == 1) {
                    const size_t idx = (size_t)grow * N + gcol;
                    outf[idx] = resid[idx] + c;
                } else {
                    if (gcol < Dsub) {
                        out0[(size_t)grow * Dsub + gcol] = f2bf(c * sigm(c));
                    } else {
                        out1[(size_t)grow * Dsub + (gcol - Dsub)] = f2bf(c);
                    }
                }
            }
        }
    }
}

// ---------------- RG-LRU scan: h = a*h + scale*(r*xp); hsg = h*g ----------------
__global__ __launch_bounds__(64)
void scan_kernel(const u16* __restrict__ R, const u16* __restrict__ XP,
                 const u16* __restrict__ G, const float* __restrict__ state,
                 const float* __restrict__ log_dec,
                 u16* __restrict__ HSG, float* __restrict__ hfin) {
    const int d = blockIdx.x * 64 + threadIdx.x;
    const int b = blockIdx.y;
    float a = sigm(log_dec[d]);
    a = fminf(fmaxf(a, 1e-6f), 1.f - 1e-6f);
    const float sc = sqrtf(fmaxf(1.f - a * a, 0.f));
    float h = state[(size_t)b * DD + d];
    size_t idx = (size_t)b * TD * DD + d;
#pragma unroll 8
    for (int t = 0; t < TD; ++t) {
        const float rv = bf2f(R[idx]);
        const float xv = bf2f(XP[idx]);
        const float gv = bf2f(G[idx]);
        h = a * h + sc * (rv * xv);
        HSG[idx] = f2bf(h * gv);
        idx += DD;
    }
    hfin[(size_t)b * DD + d] = h;
}

// ---------------- act = silu(gate)*up (gate already silu'd; in-place) ----------------
__global__ __launch_bounds__(256) void glu_mul(u16x4* __restrict__ g,
                                               const u16x4* __restrict__ u, int n4) {
    int i = blockIdx.x * blockDim.x + threadIdx.x;
    int stride = gridDim.x * blockDim.x;
    for (; i < n4; i += stride) {
        u16x4 gv = g[i], uv = u[i];
        u16x4 o = { f2bf(bf2f(gv[0]) * bf2f(uv[0])), f2bf(bf2f(gv[1]) * bf2f(uv[1])),
                    f2bf(bf2f(gv[2]) * bf2f(uv[2])), f2bf(bf2f(gv[3]) * bf2f(uv[3])) };
        g[i] = o;
    }
}

extern "C" void kernel_launch(void* const* d_in, const int* in_sizes, int n_in,
                              void* d_out, int out_size, void* d_ws, size_t ws_size,
                              hipStream_t stream) {
    const float* x       = (const float*)d_in[0];
    const float* state   = (const float*)d_in[1];
    const float* w_norm1 = (const float*)d_in[2];
    const float* W_in    = (const float*)d_in[3];
    const float* W_r     = (const float*)d_in[4];
    const float* b_r     = (const float*)d_in[5];
    const float* W_i     = (const float*)d_in[6];
    const float* b_i     = (const float*)d_in[7];
    const float* log_dec = (const float*)d_in[8];
    const float* W_out   = (const float*)d_in[9];
    const float* w_norm2 = (const float*)d_in[10];
    const float* W_gate  = (const float*)d_in[11];
    const float* W_up    = (const float*)d_in[12];
    const float* W_down  = (const float*)d_in[13];

    float* out  = (float*)d_out;
    float* hfin = out + (size_t)MD * DD;

    // workspace layout (u16 elems); lifetimes allow aliasing:
    //   bufN: n -> hsg -> n2 ;  gate spans bufR+bufG ;  up spans bufXP+spare
    u16* wstack1 = (u16*)d_ws;                              // [W_r;W_i;W_in] 3*D*D
    u16* wout2   = wstack1 + (size_t)3 * DD * DD;           // W_out D*D
    u16* wstack2 = wout2   + (size_t)DD * DD;               // [W_gate;W_up] 2*DI*D
    u16* wdown2  = wstack2 + (size_t)2 * DID * DD;          // W_down D*DI
    u16* bufN    = wdown2  + (size_t)DD * DID;              // M*D
    u16* bufR    = bufN    + (size_t)MD * DD;               // M*D
    u16* bufG    = bufR    + (size_t)MD * DD;               // M*D
    u16* bufXP   = bufG    + (size_t)MD * DD;               // M*D (+ M*D spare after)

    // 1) weight converts
    cvt_bf16<<<1024, 256, 0, stream>>>((const float4*)W_r,   (u16x4*)wstack1,                      DD*DD/4);
    cvt_bf16<<<1024, 256, 0, stream>>>((const float4*)W_i,   (u16x4*)(wstack1 + (size_t)DD*DD),    DD*DD/4);
    cvt_bf16<<<1024, 256, 0, stream>>>((const float4*)W_in,  (u16x4*)(wstack1 + (size_t)2*DD*DD),  DD*DD/4);
    cvt_bf16<<<1024, 256, 0, stream>>>((const float4*)W_out, (u16x4*)wout2,                        DD*DD/4);
    cvt_bf16<<<1024, 256, 0, stream>>>((const float4*)W_gate,(u16x4*)wstack2,                      DID*DD/4);
    cvt_bf16<<<1024, 256, 0, stream>>>((const float4*)W_up,  (u16x4*)(wstack2 + (size_t)DID*DD),   DID*DD/4);
    cvt_bf16<<<1024, 256, 0, stream>>>((const float4*)W_down,(u16x4*)wdown2,                       DD*DID/4);

    // 2) n = rmsnorm(x, w_norm1)
    rmsnorm_kernel<<<MD, 256, 0, stream>>>(x, w_norm1, bufN);

    // 3) fused r/g/xp projections
    dim3 g1(MD / 128, (3 * DD) / 128);
    gemm_bt<0><<<g1, 256, 0, stream>>>(bufN, wstack1, MD, 3 * DD, DD,
                                       b_r, b_i, nullptr, nullptr, bufR, bufG, bufXP, DD);

    // 4) RG-LRU scan -> hsg (bufN), h_final (d_out tail)
    dim3 gs(DD / 64, BD);
    scan_kernel<<<gs, 64, 0, stream>>>(bufR, bufXP, bufG, state, log_dec, bufN, hfin);

    // 5) x2 = x + hsg @ W_out^T  -> d_out (fp32)
    dim3 g2(MD / 128, DD / 128);
    gemm_bt<1><<<g2, 256, 0, stream>>>(bufN, wout2, MD, DD, DD,
                                       nullptr, nullptr, x, out, nullptr, nullptr, nullptr, 0);

    // 6) n2 = rmsnorm(x2, w_norm2)
    rmsnorm_kernel<<<MD, 256, 0, stream>>>(out, w_norm2, bufN);

    // 7) gate/up projections (gate -> bufR..bufG span, up -> bufXP..spare span)
    dim3 g3(MD / 128, (2 * DID) / 128);
    gemm_bt<2><<<g3, 256, 0, stream>>>(bufN, wstack2, MD, 2 * DID, DD,
                                       nullptr, nullptr, nullptr, nullptr, bufR, bufXP, nullptr, DID);

    // 8) act = silu(gate) * up   (in place into gate buffer)
    glu_mul<<<2048, 256, 0, stream>>>((u16x4*)bufR, (const u16x4*)bufXP, MD * DID / 4);

    // 9) out = x2 + act @ W_down^T   (in-place residual on d_out)
    dim3 g4(MD / 128, DD / 128);
    gemm_bt<1><<<g4, 256, 0, stream>>>(bufR, wdown2, MD, DD, DID,
                                       nullptr, nullptr, out, out, nullptr, nullptr, nullptr, 0);
}